// Round 1
// baseline (47.887 us; speedup 1.0000x reference)
//
#include <hip/hip_runtime.h>

// Problem: 4-level MoE routing loss, B=8, H=1024, ROUTE=64, 16x16 patches/level.
// d_in order (setup_inputs dict order): out0, gt0, out1, gt1, out2, gt2, out3, gt3
// d_out layout (float32, concatenated return order):
//   [0]                 loss (1)
//   [1 .. 8388609)      label_patch (8,1,1024,1024)
//   [8388609 .. +2048)  moe_label (8,1,16,16)  -- written as float 0..3
//   [8390657 .. +8192)  score (8,4,16,16)
// ws: patchErr float[4][2048] @0 (32KB), moe int[2048] @32768

#define NPATCH 2048   // 8 * 256

// ---------------- Kernel A: per-patch err/gt sums + score ----------------
__global__ __launch_bounds__(256) void score_kernel(
    const float* __restrict__ out0, const float* __restrict__ gt0,
    const float* __restrict__ out1, const float* __restrict__ gt1,
    const float* __restrict__ out2, const float* __restrict__ gt2,
    const float* __restrict__ out3, const float* __restrict__ gt3,
    float* __restrict__ patchErr,   // [4][2048]
    float* __restrict__ scoreOut)   // (B,4,16,16)
{
    const int bx = blockIdx.x;
    const int level = bx >> 11;        // 0..3
    const int p = bx & 2047;           // b*256 + l
    const int b = p >> 8;
    const int l = p & 255;
    const int py = l >> 4, px = l & 15;

    const float* po; const float* pg; int k, W, kvShift;
    switch (level) {
        case 0:  po = out0; pg = gt0; k = 64; W = 1024; kvShift = 4; break;
        case 1:  po = out1; pg = gt1; k = 32; W = 512;  kvShift = 3; break;
        case 2:  po = out2; pg = gt2; k = 16; W = 256;  kvShift = 2; break;
        default: po = out3; pg = gt3; k = 8;  W = 128;  kvShift = 1; break;
    }
    const int kv = k >> 2;                 // float4s per patch row
    const int nvec = k * kv;               // float4s per patch
    const int rowBase = py * k, colBase = px * k;
    const size_t imgBase = (size_t)b * W * W;

    float err = 0.f, gts = 0.f;
    for (int idx = threadIdx.x; idx < nvec; idx += 256) {
        int r = idx >> kvShift;
        int c = (idx & (kv - 1)) << 2;
        size_t off = imgBase + (size_t)(rowBase + r) * W + (colBase + c);
        float4 o = *(const float4*)(po + off);
        float4 g = *(const float4*)(pg + off);
        float dx = o.x - g.x, dy = o.y - g.y, dz = o.z - g.z, dw = o.w - g.w;
        err += dx * dx + dy * dy + dz * dz + dw * dw;
        gts += g.x + g.y + g.z + g.w;
    }
    // wave64 shuffle reduce
    for (int s = 32; s; s >>= 1) {
        err += __shfl_down(err, s, 64);
        gts += __shfl_down(gts, s, 64);
    }
    __shared__ float se[4], sg[4];
    const int wave = threadIdx.x >> 6, lane = threadIdx.x & 63;
    if (lane == 0) { se[wave] = err; sg[wave] = gts; }
    __syncthreads();
    if (threadIdx.x == 0) {
        float e = se[0] + se[1] + se[2] + se[3];
        float g = sg[0] + sg[1] + sg[2] + sg[3];
        patchErr[level * NPATCH + p] = e;
        scoreOut[b * 1024 + level * 256 + l] = e / (float)(k * k) + e / (g + 1e-10f);
    }
}

// ---------------- Kernel B: argmin -> moe, loss reduce ----------------
__global__ __launch_bounds__(256) void moe_loss_kernel(
    const float* __restrict__ patchErr,   // [4][2048]
    const float* __restrict__ scoreOut,   // (B,4,16,16)
    float* __restrict__ lossOut,          // d_out[0]
    float* __restrict__ moeF,             // d_out moe region (float)
    int* __restrict__ moeI)               // ws int copy
{
    double s0 = 0, s1 = 0, s2 = 0, s3 = 0;
    for (int p = threadIdx.x; p < NPATCH; p += 256) {
        int b = p >> 8, l = p & 255;
        const float* sc = scoreOut + b * 1024 + l;
        float best = sc[0]; int m = 0;
        #pragma unroll
        for (int i = 1; i < 4; ++i) {
            float v = sc[i * 256];
            if (v < best) { best = v; m = i; }   // strict < = first-min (np.argmin)
        }
        moeF[p] = (float)m;
        moeI[p] = m;
        s0 += (double)patchErr[p];
        if (m >= 1) s1 += (double)patchErr[NPATCH + p];
        if (m >= 2) s2 += (double)patchErr[2 * NPATCH + p];
        if (m >= 3) s3 += (double)patchErr[3 * NPATCH + p];
    }
    for (int s = 32; s; s >>= 1) {
        s0 += __shfl_down(s0, s, 64);
        s1 += __shfl_down(s1, s, 64);
        s2 += __shfl_down(s2, s, 64);
        s3 += __shfl_down(s3, s, 64);
    }
    __shared__ double sd[4][4];
    const int wave = threadIdx.x >> 6, lane = threadIdx.x & 63;
    if (lane == 0) { sd[0][wave] = s0; sd[1][wave] = s1; sd[2][wave] = s2; sd[3][wave] = s3; }
    __syncthreads();
    if (threadIdx.x == 0) {
        double t0 = sd[0][0] + sd[0][1] + sd[0][2] + sd[0][3];
        double t1 = sd[1][0] + sd[1][1] + sd[1][2] + sd[1][3];
        double t2 = sd[2][0] + sd[2][1] + sd[2][2] + sd[2][3];
        double t3 = sd[3][0] + sd[3][1] + sd[3][2] + sd[3][3];
        double loss = t0 / 8388608.0 + t1 / 2097152.0 + t2 / 524288.0 + t3 / 131072.0;
        lossOut[0] = (float)loss;
    }
}

// ---------------- Kernel C: label_patch assembly ----------------
__global__ __launch_bounds__(256) void label_kernel(
    const float* __restrict__ gt0, const float* __restrict__ gt1,
    const float* __restrict__ gt2, const float* __restrict__ gt3,
    const int* __restrict__ moe, float* __restrict__ lab)
{
    int g = blockIdx.x * 256 + threadIdx.x;     // pixel index < 8388608
    int b = g >> 20;
    int rem = g & 1048575;
    int y = rem >> 10, x = rem & 1023;
    int py = y >> 6, px = x >> 6;
    int m = moe[(b << 8) + (py << 4) + px];
    float v;
    if (m == 0) {
        v = gt0[g];
    } else {
        int k = 64 >> m, pad = (64 - k) >> 1, W = 1024 >> m;
        int iy = (y & 63) - pad;
        int ix = (x & 63) - pad;
        if ((unsigned)iy < (unsigned)k && (unsigned)ix < (unsigned)k) {
            const float* gt = (m == 1) ? gt1 : (m == 2) ? gt2 : gt3;
            v = gt[b * W * W + (py * k + iy) * W + (px * k + ix)];
        } else {
            v = 0.2f;
        }
    }
    lab[g] = v;
}

extern "C" void kernel_launch(void* const* d_in, const int* in_sizes, int n_in,
                              void* d_out, int out_size, void* d_ws, size_t ws_size,
                              hipStream_t stream) {
    const float* out0 = (const float*)d_in[0];
    const float* gt0  = (const float*)d_in[1];
    const float* out1 = (const float*)d_in[2];
    const float* gt1  = (const float*)d_in[3];
    const float* out2 = (const float*)d_in[4];
    const float* gt2  = (const float*)d_in[5];
    const float* out3 = (const float*)d_in[6];
    const float* gt3  = (const float*)d_in[7];

    float* o = (float*)d_out;
    float* lossOut  = o;
    float* labOut   = o + 1;
    float* moeFOut  = o + 8388609;
    float* scoreOut = o + 8390657;

    float* patchErr = (float*)d_ws;
    int*   moeI     = (int*)((char*)d_ws + 32768);

    score_kernel<<<8192, 256, 0, stream>>>(out0, gt0, out1, gt1, out2, gt2,
                                           out3, gt3, patchErr, scoreOut);
    moe_loss_kernel<<<1, 256, 0, stream>>>(patchErr, scoreOut, lossOut, moeFOut, moeI);
    label_kernel<<<32768, 256, 0, stream>>>(gt0, gt1, gt2, gt3, moeI, labOut);
}

// Round 2
// 38.013 us; speedup vs baseline: 1.2598x; 1.2598x over previous
//
#include <hip/hip_runtime.h>

// 4-level MoE routing loss, B=8, H=1024, ROUTE=64, 16x16 patches/level.
// d_in order: out0, gt0, out1, gt1, out2, gt2, out3, gt3   (all fp32)
// d_out (fp32, flat, return order):
//   [0]                  loss (1)
//   [1 .. 8388609)       label_patch (8,1,1024,1024)
//   [8388609 .. +2048)   moe_label (8,1,16,16) as float 0..3
//   [8390657 .. +8192)   score (8,4,16,16)
// ws: lossTerm double[2048] @0 (16KB), moeI int[2048] @16384
//
// Structure (R2): fused per-patch kernel — block p computes err/gt sums for
// patch p at ALL 4 levels (block-local), then score, argmin, moe, and the
// per-patch loss contribution  sum_{i<=m} e_i/N_i  (the masked MSE loss
// decomposes exactly into per-patch patchErr sums — no image re-read).
// Kernel B assembles label_patch (1 px/thread); its block 0 additionally
// reduces the 2048 loss terms in a fixed (deterministic) order.

#define NPATCH 2048   // 8 * 256

__global__ __launch_bounds__(256) void fused_score_kernel(
    const float* __restrict__ out0, const float* __restrict__ gt0,
    const float* __restrict__ out1, const float* __restrict__ gt1,
    const float* __restrict__ out2, const float* __restrict__ gt2,
    const float* __restrict__ out3, const float* __restrict__ gt3,
    float* __restrict__ scoreOut,   // (B,4,16,16)
    float* __restrict__ moeF,       // d_out moe region (float)
    int* __restrict__ moeI,         // ws int copy
    double* __restrict__ lossTerm)  // ws [2048]
{
    const int p = blockIdx.x;          // 0..2047 : b*256 + l
    const int b = p >> 8;
    const int l = p & 255;
    const int py = l >> 4, px = l & 15;

    const float* PO[4] = {out0, out1, out2, out3};
    const float* PG[4] = {gt0, gt1, gt2, gt3};

    float err[4], gts[4];

    #pragma unroll
    for (int lev = 0; lev < 4; ++lev) {
        const int k  = 64 >> lev;          // 64,32,16,8 (compile-time)
        const int W  = 1024 >> lev;
        const int kv = k >> 2;             // float4s per patch row
        const int nvec = k * kv;
        const int rowBase = py * k, colBase = px * k;
        const size_t base = (size_t)b * W * W;
        const float* po = PO[lev];
        const float* pg = PG[lev];

        float e = 0.f, g = 0.f;
        for (int idx = threadIdx.x; idx < nvec; idx += 256) {
            int r = idx / kv;              // kv is constexpr pow2 -> shifts
            int c = (idx % kv) * 4;
            size_t off = base + (size_t)(rowBase + r) * W + (colBase + c);
            float4 o = *(const float4*)(po + off);
            float4 q = *(const float4*)(pg + off);
            float dx = o.x - q.x, dy = o.y - q.y, dz = o.z - q.z, dw = o.w - q.w;
            e += dx * dx + dy * dy + dz * dz + dw * dw;
            g += q.x + q.y + q.z + q.w;
        }
        err[lev] = e; gts[lev] = g;
    }

    // wave64 shuffle reduce (all 8 accumulators)
    for (int s = 32; s; s >>= 1) {
        #pragma unroll
        for (int i = 0; i < 4; ++i) {
            err[i] += __shfl_down(err[i], s, 64);
            gts[i] += __shfl_down(gts[i], s, 64);
        }
    }
    __shared__ float se[4][4], sg[4][4];
    const int wave = threadIdx.x >> 6, lane = threadIdx.x & 63;
    if (lane == 0) {
        #pragma unroll
        for (int i = 0; i < 4; ++i) { se[i][wave] = err[i]; sg[i][wave] = gts[i]; }
    }
    __syncthreads();
    if (threadIdx.x == 0) {
        float E[4], S[4];
        #pragma unroll
        for (int i = 0; i < 4; ++i) {
            E[i] = se[i][0] + se[i][1] + se[i][2] + se[i][3];
            float G = sg[i][0] + sg[i][1] + sg[i][2] + sg[i][3];
            float kk = (float)((64 >> i) * (64 >> i));
            S[i] = E[i] / kk + E[i] / (G + 1e-10f);
            scoreOut[b * 1024 + i * 256 + l] = S[i];
        }
        int m = 0; float best = S[0];
        #pragma unroll
        for (int i = 1; i < 4; ++i)
            if (S[i] < best) { best = S[i]; m = i; }   // strict < : first-min
        moeF[p] = (float)m;
        moeI[p] = m;
        double t = (double)E[0] / 8388608.0;           // level 0 always counted
        if (m >= 1) t += (double)E[1] / 2097152.0;
        if (m >= 2) t += (double)E[2] / 524288.0;
        if (m >= 3) t += (double)E[3] / 131072.0;
        lossTerm[p] = t;
    }
}

__global__ __launch_bounds__(256) void label_loss_kernel(
    const float* __restrict__ gt0, const float* __restrict__ gt1,
    const float* __restrict__ gt2, const float* __restrict__ gt3,
    const int* __restrict__ moe, const double* __restrict__ lossTerm,
    float* __restrict__ lossOut, float* __restrict__ lab)
{
    if (blockIdx.x == 0) {
        // deterministic loss reduction: fixed assignment + fixed tree
        double t = 0.0;
        for (int i = threadIdx.x; i < NPATCH; i += 256) t += lossTerm[i];
        for (int s = 32; s; s >>= 1) t += __shfl_down(t, s, 64);
        __shared__ double sd[4];
        const int wave = threadIdx.x >> 6, lane = threadIdx.x & 63;
        if (lane == 0) sd[wave] = t;
        __syncthreads();
        if (threadIdx.x == 0)
            lossOut[0] = (float)(sd[0] + sd[1] + sd[2] + sd[3]);
    }

    int g = blockIdx.x * 256 + threadIdx.x;   // pixel index, grid covers exactly
    int b = g >> 20;
    int rem = g & 1048575;
    int y = rem >> 10, x = rem & 1023;
    int py = y >> 6, px = x >> 6;
    int m = moe[(b << 8) + (py << 4) + px];
    float v;
    if (m == 0) {
        v = gt0[g];
    } else {
        int k = 64 >> m, pad = (64 - k) >> 1, W = 1024 >> m;
        int iy = (y & 63) - pad;
        int ix = (x & 63) - pad;
        if ((unsigned)iy < (unsigned)k && (unsigned)ix < (unsigned)k) {
            const float* gt = (m == 1) ? gt1 : (m == 2) ? gt2 : gt3;
            v = gt[b * W * W + (py * k + iy) * W + (px * k + ix)];
        } else {
            v = 0.2f;
        }
    }
    lab[g] = v;
}

extern "C" void kernel_launch(void* const* d_in, const int* in_sizes, int n_in,
                              void* d_out, int out_size, void* d_ws, size_t ws_size,
                              hipStream_t stream) {
    const float* out0 = (const float*)d_in[0];
    const float* gt0  = (const float*)d_in[1];
    const float* out1 = (const float*)d_in[2];
    const float* gt1  = (const float*)d_in[3];
    const float* out2 = (const float*)d_in[4];
    const float* gt2  = (const float*)d_in[5];
    const float* out3 = (const float*)d_in[6];
    const float* gt3  = (const float*)d_in[7];

    float* o = (float*)d_out;
    float* lossOut  = o;
    float* labOut   = o + 1;
    float* moeFOut  = o + 8388609;
    float* scoreOut = o + 8390657;

    double* lossTerm = (double*)d_ws;
    int*    moeI     = (int*)((char*)d_ws + 16384);

    fused_score_kernel<<<NPATCH, 256, 0, stream>>>(
        out0, gt0, out1, gt1, out2, gt2, out3, gt3,
        scoreOut, moeFOut, moeI, lossTerm);
    label_loss_kernel<<<32768, 256, 0, stream>>>(
        gt0, gt1, gt2, gt3, moeI, lossTerm, lossOut, labOut);
}